// Round 8
// baseline (893.303 us; speedup 1.0000x reference)
//
#include <hip/hip_runtime.h>
#include <hip/hip_bf16.h>
#include <stdint.h>

#define D 512
#define LN_EPS 1e-5f

typedef __attribute__((ext_vector_type(8))) short bf16x8;
typedef __attribute__((ext_vector_type(4))) float f32x4;

__device__ __forceinline__ unsigned short f32_to_bf16_bits(float x) {
    unsigned int u = __float_as_uint(x);
    u += 0x7fffu + ((u >> 16) & 1u);   // round-to-nearest-even
    return (unsigned short)(u >> 16);
}
__device__ __forceinline__ float bf16lo(unsigned int u) { return __uint_as_float(u << 16); }
__device__ __forceinline__ float bf16hi(unsigned int u) { return __uint_as_float(u & 0xffff0000u); }
__device__ __forceinline__ float bf16s(short s) { return __uint_as_float(((unsigned int)(unsigned short)s) << 16); }

typedef const __attribute__((address_space(1))) unsigned int GU;
typedef __attribute__((address_space(3))) unsigned int LU;
__device__ __forceinline__ void gload_lds16(const void* g, void* l) {
    __builtin_amdgcn_global_load_lds((GU*)g, (LU*)l, 16, 0, 0);
}

// ---------------- fused preprocessing: cast x0, cast W, init deg/cnt ----------------
__global__ void k_prep(const float4* __restrict__ x0, ushort4* __restrict__ xb4,
                       const float4* __restrict__ Ws4, ushort4* __restrict__ wb4,
                       float* __restrict__ deg, int* __restrict__ cnt,
                       long nx4, long nxin4, long nw4, int N) {
    long id = (long)blockIdx.x * blockDim.x + threadIdx.x;
    if (id < nx4) {
        float4 v;
        if (id < nxin4) v = x0[id];
        else { v.x = 0.f; v.y = 0.f; v.z = 0.f; v.w = 0.f; }
        ushort4 o;
        o.x = f32_to_bf16_bits(v.x);
        o.y = f32_to_bf16_bits(v.y);
        o.z = f32_to_bf16_bits(v.z);
        o.w = f32_to_bf16_bits(v.w);
        xb4[id] = o;
    } else if (id < nx4 + nw4) {
        long i = id - nx4;
        float4 v = Ws4[i];
        ushort4 o;
        o.x = f32_to_bf16_bits(v.x);
        o.y = f32_to_bf16_bits(v.y);
        o.z = f32_to_bf16_bits(v.z);
        o.w = f32_to_bf16_bits(v.w);
        wb4[i] = o;
    } else {
        long i = id - nx4 - nw4;
        if (i < N) { deg[i] = 1.0f; cnt[i] = 1; }   // self-loop weight 1, count 1
    }
}

__global__ void k_deg_cnt(const int* __restrict__ col, const float* __restrict__ ew,
                          float* deg, int* cnt, int E) {
    int e = blockIdx.x * blockDim.x + threadIdx.x;
    if (e < E) {
        int c = col[e];
        atomicAdd(&deg[c], ew[e]);
        atomicAdd(&cnt[c], 1);
    }
}

// single block: dinv = rsqrt(deg) in place, then coalesced wave-scan of cnt -> rptr/cur
__global__ __launch_bounds__(1024) void k_scan(const int* __restrict__ cnt,
                                               float* __restrict__ deg,
                                               int* __restrict__ rptr,
                                               int* __restrict__ cur, int n) {
    for (int i = threadIdx.x; i < n; i += 1024) deg[i] = rsqrtf(deg[i]);

    const int tid = threadIdx.x, lane = tid & 63, wv = tid >> 6;   // 16 waves
    const int chunk = (n + 15) >> 4;
    const int wbeg = wv * chunk;
    const int wend = min(wbeg + chunk, n);

    int tot = 0;
    for (int i = wbeg + lane; i < wend; i += 64) tot += cnt[i];
#pragma unroll
    for (int off = 32; off > 0; off >>= 1) tot += __shfl_xor(tot, off);
    __shared__ int woff[17];
    if (lane == 0) woff[wv] = tot;
    __syncthreads();
    if (tid == 0) {
        int r = 0;
        for (int w = 0; w < 16; ++w) { int t = woff[w]; woff[w] = r; r += t; }
        woff[16] = r;
    }
    __syncthreads();

    int run = woff[wv];
    for (int base = wbeg; base < wend; base += 64) {
        int i = base + lane;
        int v = (i < wend) ? cnt[i] : 0;
        int inc = v;
#pragma unroll
        for (int off = 1; off < 64; off <<= 1) {
            int u = __shfl_up(inc, off);
            if (lane >= off) inc += u;
        }
        if (i < wend) {
            int excl = run + inc - v;
            rptr[i] = excl;
            cur[i] = excl;
        }
        run += __shfl(inc, 63);
    }
    if (tid == 0) rptr[n] = woff[16];
}

// fused self-loop + edge fill, single 8B scatter per entry
__global__ void k_fill(const int* __restrict__ row, const int* __restrict__ col,
                       const float* __restrict__ ew, const float* __restrict__ dinv,
                       int* cur, uint2* __restrict__ srcval, int N, int E) {
    int i = blockIdx.x * blockDim.x + threadIdx.x;
    if (i < N) {
        int slot = atomicAdd(&cur[i], 1);
        float d = dinv[i];
        uint2 sv; sv.x = (unsigned)i; sv.y = __float_as_uint(d * d);
        srcval[slot] = sv;
    } else if (i < N + E) {
        int e = i - N;
        int r = row[e], c = col[e];
        int slot = atomicAdd(&cur[c], 1);
        uint2 sv; sv.x = (unsigned)r;
        sv.y = __float_as_uint(dinv[r] * ew[e] * dinv[c]);
        srcval[slot] = sv;
    }
}

// ---------------- pure gather: g[t] = sum_e val_e * x[src_e]  (bf16 in/out) ----------------
// ONE WAVE per target node. Lane owns 8 cols (uint4). Edge (src,val) loaded
// coalesced 64-at-a-time, broadcast via shfl. x2 unroll, dual acc banks.
__global__ __launch_bounds__(256) void k_agg(
    const uint4* __restrict__ X4,       // x bf16 [Mpad][64] uint4
    const int* __restrict__ rptr,
    const uint2* __restrict__ srcval,
    uint4* __restrict__ G4,             // g bf16 out [Mpad][64]
    int N) {
    const int wv = threadIdx.x >> 6, lane = threadIdx.x & 63;
    const int t = blockIdx.x * 4 + wv;
    if (t >= N) return;
    const int beg = rptr[t], end = rptr[t + 1];

    float a[8], b[8];
#pragma unroll
    for (int i = 0; i < 8; ++i) { a[i] = 0.f; b[i] = 0.f; }

    for (int base = beg; base < end; base += 64) {
        int m = end - base;
        if (m > 64) m = 64;
        int idx = base + lane;
        if (idx > end - 1) idx = end - 1;
        uint2 svl = srcval[idx];
        int e = 0;
        for (; e + 2 <= m; e += 2) {
            unsigned s0 = __shfl(svl.x, e);
            unsigned s1 = __shfl(svl.x, e + 1);
            float w0 = __uint_as_float(__shfl(svl.y, e));
            float w1 = __uint_as_float(__shfl(svl.y, e + 1));
            uint4 u0 = X4[(size_t)s0 * 64 + lane];
            uint4 u1 = X4[(size_t)s1 * 64 + lane];
            a[0] = fmaf(w0, bf16lo(u0.x), a[0]);
            a[1] = fmaf(w0, bf16hi(u0.x), a[1]);
            a[2] = fmaf(w0, bf16lo(u0.y), a[2]);
            a[3] = fmaf(w0, bf16hi(u0.y), a[3]);
            a[4] = fmaf(w0, bf16lo(u0.z), a[4]);
            a[5] = fmaf(w0, bf16hi(u0.z), a[5]);
            a[6] = fmaf(w0, bf16lo(u0.w), a[6]);
            a[7] = fmaf(w0, bf16hi(u0.w), a[7]);
            b[0] = fmaf(w1, bf16lo(u1.x), b[0]);
            b[1] = fmaf(w1, bf16hi(u1.x), b[1]);
            b[2] = fmaf(w1, bf16lo(u1.y), b[2]);
            b[3] = fmaf(w1, bf16hi(u1.y), b[3]);
            b[4] = fmaf(w1, bf16lo(u1.z), b[4]);
            b[5] = fmaf(w1, bf16hi(u1.z), b[5]);
            b[6] = fmaf(w1, bf16lo(u1.w), b[6]);
            b[7] = fmaf(w1, bf16hi(u1.w), b[7]);
        }
        if (e < m) {
            unsigned s0 = __shfl(svl.x, e);
            float w0 = __uint_as_float(__shfl(svl.y, e));
            uint4 u0 = X4[(size_t)s0 * 64 + lane];
            a[0] = fmaf(w0, bf16lo(u0.x), a[0]);
            a[1] = fmaf(w0, bf16hi(u0.x), a[1]);
            a[2] = fmaf(w0, bf16lo(u0.y), a[2]);
            a[3] = fmaf(w0, bf16hi(u0.y), a[3]);
            a[4] = fmaf(w0, bf16lo(u0.z), a[4]);
            a[5] = fmaf(w0, bf16hi(u0.z), a[5]);
            a[6] = fmaf(w0, bf16lo(u0.w), a[6]);
            a[7] = fmaf(w0, bf16hi(u0.w), a[7]);
        }
    }
#pragma unroll
    for (int i = 0; i < 8; ++i) a[i] += b[i];

    uint4 pk;
    pk.x = ((unsigned)f32_to_bf16_bits(a[1]) << 16) | f32_to_bf16_bits(a[0]);
    pk.y = ((unsigned)f32_to_bf16_bits(a[3]) << 16) | f32_to_bf16_bits(a[2]);
    pk.z = ((unsigned)f32_to_bf16_bits(a[5]) << 16) | f32_to_bf16_bits(a[4]);
    pk.w = ((unsigned)f32_to_bf16_bits(a[7]) << 16) | f32_to_bf16_bits(a[6]);
    G4[(size_t)t * 64 + lane] = pk;
}

// ---------------- GEMM + bias + LN + relu + residual (fused epilogue) ----------------
// H' = G @ W^T + b, x' = [relu](LN(H')) + xb.  BM=128, BN=512 (full row per
// block -> per-row LN is block-local), BK=32, 512 threads (8 waves 2Mx4N,
// wave tile 64x128), 2-phase dbuf, LDS 80KB -> 2 blocks/CU.
// Epilogue reduction LDS aliases As (safe: after final K-loop barrier).
__global__ __launch_bounds__(512) void k_gemm_ln(
    const short* __restrict__ A,       // g bf16 [Mpad][512]
    const short* __restrict__ W,       // wb layer [512][512]
    const float* __restrict__ bias,    // [512]
    const float* __restrict__ gamma,
    const float* __restrict__ beta,
    short* __restrict__ xb,            // identity in / next-x out (bf16)
    float* __restrict__ out_f32,       // [N][512] final out (last layer)
    int N, int last) {
    __shared__ short As[2][128 * 32];   // 8 KB x2
    __shared__ short Bs[2][512 * 32];   // 32 KB x2
    const int tid = threadIdx.x;
    const int wave = tid >> 6, lane = tid & 63;
    const int wmg = wave >> 2, wng = wave & 3;
    const int wm = wmg * 64, wn0 = wng * 128;
    const int tm = blockIdx.x * 128;
    f32x4 acc[4][8] = {};
    const int fr = lane & 15, fc = lane >> 4;

    const int r0 = tid >> 2, cb0 = (tid & 3) * 8;   // 128 rows x 4 chunks of 8
    const short* Ab = A + (size_t)(tm + r0) * 512 + cb0;
    const short* Wb = W + (size_t)r0 * 512 + cb0;

    // prologue: stage k0=0 into buffer 0
    gload_lds16(Ab,                     &As[0][tid * 8]);
    gload_lds16(Wb,                     &Bs[0][tid * 8]);
    gload_lds16(Wb + (size_t)128 * 512, &Bs[0][(tid + 512) * 8]);
    gload_lds16(Wb + (size_t)256 * 512, &Bs[0][(tid + 1024) * 8]);
    gload_lds16(Wb + (size_t)384 * 512, &Bs[0][(tid + 1536) * 8]);
    __syncthreads();

    int cur = 0;
    for (int k0 = 0; k0 < 512; k0 += 32) {
        const int kn = k0 + 32;
        if (kn < 512) {
            gload_lds16(Ab + kn,                     &As[cur ^ 1][tid * 8]);
            gload_lds16(Wb + kn,                     &Bs[cur ^ 1][tid * 8]);
            gload_lds16(Wb + (size_t)128 * 512 + kn, &Bs[cur ^ 1][(tid + 512) * 8]);
            gload_lds16(Wb + (size_t)256 * 512 + kn, &Bs[cur ^ 1][(tid + 1024) * 8]);
            gload_lds16(Wb + (size_t)384 * 512 + kn, &Bs[cur ^ 1][(tid + 1536) * 8]);
        }
        bf16x8 af[4], bfr[8];
#pragma unroll
        for (int m = 0; m < 4; ++m)
            af[m] = *(const bf16x8*)&As[cur][(wm + m * 16 + fr) * 32 + fc * 8];
#pragma unroll
        for (int n = 0; n < 8; ++n)
            bfr[n] = *(const bf16x8*)&Bs[cur][(wn0 + n * 16 + fr) * 32 + fc * 8];
#pragma unroll
        for (int m = 0; m < 4; ++m) {
#pragma unroll
            for (int n = 0; n < 8; ++n)
                acc[m][n] = __builtin_amdgcn_mfma_f32_16x16x32_bf16(af[m], bfr[n], acc[m][n], 0, 0, 0);
        }
        __syncthreads();
        cur ^= 1;
    }

    // ---- epilogue: bias + per-row LN (block-local) + relu + residual ----
    float2* part  = (float2*)&As[0][0];   // [2][4][64]  (4 KB)
    float2* stats = (float2*)&As[1][0];   // [2][64]     (1 KB)

    const int c0 = wn0 + fr;              // lane's col base; cols c0 + n*16
    float bv[8], gv[8], btv[8];
#pragma unroll
    for (int n = 0; n < 8; ++n) {
        bv[n]  = bias[c0 + n * 16];
        gv[n]  = gamma[c0 + n * 16];
        btv[n] = beta[c0 + n * 16];
    }
    // per-row partial sums (reduce over this wave's 128 cols)
#pragma unroll
    for (int m = 0; m < 4; ++m) {
#pragma unroll
        for (int j = 0; j < 4; ++j) {
            float s1 = 0.f, s2 = 0.f;
#pragma unroll
            for (int n = 0; n < 8; ++n) {
                float v = acc[m][n][j] + bv[n];
                s1 += v;
                s2 += v * v;
            }
#pragma unroll
            for (int off = 1; off < 16; off <<= 1) {
                s1 += __shfl_xor(s1, off);
                s2 += __shfl_xor(s2, off);
            }
            if (fr == 0) {
                float2 p; p.x = s1; p.y = s2;
                part[(wmg * 4 + wng) * 64 + fc * 4 + m * 16 + j] = p;
            }
        }
    }
    __syncthreads();
    if (tid < 128) {
        int rl = tid & 63, g = tid >> 6;
        float s1 = 0.f, s2 = 0.f;
#pragma unroll
        for (int w = 0; w < 4; ++w) {
            float2 p = part[(g * 4 + w) * 64 + rl];
            s1 += p.x; s2 += p.y;
        }
        float mean = s1 * (1.0f / 512.0f);
        float var = s2 * (1.0f / 512.0f) - mean * mean;
        float2 st; st.x = mean; st.y = rsqrtf(var + LN_EPS);
        stats[g * 64 + rl] = st;
    }
    __syncthreads();

#pragma unroll
    for (int m = 0; m < 4; ++m) {
#pragma unroll
        for (int j = 0; j < 4; ++j) {
            const int rl = fc * 4 + m * 16 + j;
            const float2 st = stats[wmg * 64 + rl];
            const int r = tm + wm + rl;
            const size_t rb = (size_t)r * 512;
#pragma unroll
            for (int n = 0; n < 8; ++n) {
                const int c = c0 + n * 16;
                float v = acc[m][n][j] + bv[n];
                float o = (v - st.x) * st.y * gv[n] + btv[n];
                if (!last) o = fmaxf(o, 0.f);
                o += bf16s(xb[rb + c]);
                if (last) {
                    if (r < N) out_f32[rb + c] = o;
                } else {
                    xb[rb + c] = (short)f32_to_bf16_bits(o);
                }
            }
        }
    }
}

extern "C" void kernel_launch(void* const* d_in, const int* in_sizes, int n_in,
                              void* d_out, int out_size, void* d_ws, size_t ws_size,
                              hipStream_t stream) {
    const float* x0     = (const float*)d_in[0];
    const int*   ei     = (const int*)d_in[1];
    const float* ew     = (const float*)d_in[2];
    const float* Ws     = (const float*)d_in[3];
    const float* bs     = (const float*)d_in[4];
    const float* gammas = (const float*)d_in[5];
    const float* betas  = (const float*)d_in[6];

    const int N = in_sizes[0] / D;         // 50000
    const int E = in_sizes[1] / 2;         // 800000
    const int L = in_sizes[3] / (D * D);   // 3
    const int Mpad = (N + 127) & ~127;     // 50048

    char* p = (char*)d_ws;
    auto carve = [&](size_t bytes) {
        char* q = p;
        p += (bytes + 255) & ~(size_t)255;
        return (void*)q;
    };
    short* xb     = (short*)carve((size_t)Mpad * D * 2);   // x bf16 (padded)
    short* gb     = (short*)carve((size_t)Mpad * D * 2);   // g = Ax bf16 (padded)
    short* wb     = (short*)carve((size_t)L * D * D * 2);  // W bf16
    float* dinv   = (float*)carve((size_t)N * 4);          // deg -> dinv in place
    int*   cnt    = (int*)carve((size_t)N * 4);
    int*   rptr   = (int*)carve((size_t)(N + 1) * 4);
    int*   cur    = (int*)carve((size_t)N * 4);
    uint2* srcval = (uint2*)carve((size_t)(E + N) * 8);
    (void)ws_size; (void)n_in; (void)out_size;

    const int* rowI = ei;
    const int* colI = ei + E;

    // fused preprocessing: cast x0 (+pad), cast W, init deg/cnt
    {
        long nx4 = (long)Mpad * D / 4, nxin4 = (long)N * D / 4;
        long nw4 = (long)L * D * D / 4;
        long tot = nx4 + nw4 + N;
        k_prep<<<(int)((tot + 255) / 256), 256, 0, stream>>>(
            (const float4*)x0, (ushort4*)xb, (const float4*)Ws, (ushort4*)wb,
            dinv, cnt, nx4, nxin4, nw4, N);
    }
    k_deg_cnt<<<(E + 255) / 256, 256, 0, stream>>>(colI, ew, dinv, cnt, E);
    k_scan<<<1, 1024, 0, stream>>>(cnt, dinv, rptr, cur, N);
    k_fill<<<(N + E + 255) / 256, 256, 0, stream>>>(rowI, colI, ew, dinv, cur, srcval, N, E);

    for (int l = 0; l < L; ++l) {
        int last = (l == L - 1);
        // g = A_hat * x   (gather-first; A_hat(XW) == (A_hat X) W)
        k_agg<<<(N + 3) / 4, 256, 0, stream>>>(
            (const uint4*)xb, rptr, srcval, (uint4*)gb, N);
        // h = g W^T + b; x' = [relu](LN(h)) + x   (fused epilogue)
        k_gemm_ln<<<Mpad / 128, 512, 0, stream>>>(
            gb, wb + (size_t)l * D * D,
            bs + (size_t)l * D, gammas + (size_t)l * D, betas + (size_t)l * D,
            xb, (float*)d_out, N, last);
    }
}

// Round 9
// 685.215 us; speedup vs baseline: 1.3037x; 1.3037x over previous
//
#include <hip/hip_runtime.h>
#include <hip/hip_bf16.h>
#include <stdint.h>

#define D 512
#define LN_EPS 1e-5f

typedef __attribute__((ext_vector_type(8))) short bf16x8;
typedef __attribute__((ext_vector_type(4))) float f32x4;

__device__ __forceinline__ unsigned short f32_to_bf16_bits(float x) {
    unsigned int u = __float_as_uint(x);
    u += 0x7fffu + ((u >> 16) & 1u);   // round-to-nearest-even
    return (unsigned short)(u >> 16);
}
__device__ __forceinline__ float bf16lo(unsigned int u) { return __uint_as_float(u << 16); }
__device__ __forceinline__ float bf16hi(unsigned int u) { return __uint_as_float(u & 0xffff0000u); }

typedef const __attribute__((address_space(1))) unsigned int GU;
typedef __attribute__((address_space(3))) unsigned int LU;
__device__ __forceinline__ void gload_lds16(const void* g, void* l) {
    __builtin_amdgcn_global_load_lds((GU*)g, (LU*)l, 16, 0, 0);
}

// ---------------- fused preprocessing: cast x0, cast W, init deg/cnt ----------------
__global__ void k_prep(const float4* __restrict__ x0, ushort4* __restrict__ xb4,
                       const float4* __restrict__ Ws4, ushort4* __restrict__ wb4,
                       float* __restrict__ deg, int* __restrict__ cnt,
                       long nx4, long nxin4, long nw4, int N) {
    long id = (long)blockIdx.x * blockDim.x + threadIdx.x;
    if (id < nx4) {
        float4 v;
        if (id < nxin4) v = x0[id];
        else { v.x = 0.f; v.y = 0.f; v.z = 0.f; v.w = 0.f; }
        ushort4 o;
        o.x = f32_to_bf16_bits(v.x);
        o.y = f32_to_bf16_bits(v.y);
        o.z = f32_to_bf16_bits(v.z);
        o.w = f32_to_bf16_bits(v.w);
        xb4[id] = o;
    } else if (id < nx4 + nw4) {
        long i = id - nx4;
        float4 v = Ws4[i];
        ushort4 o;
        o.x = f32_to_bf16_bits(v.x);
        o.y = f32_to_bf16_bits(v.y);
        o.z = f32_to_bf16_bits(v.z);
        o.w = f32_to_bf16_bits(v.w);
        wb4[i] = o;
    } else {
        long i = id - nx4 - nw4;
        if (i < N) { deg[i] = 1.0f; cnt[i] = 1; }   // self-loop weight 1, count 1
    }
}

__global__ void k_deg_cnt(const int* __restrict__ col, const float* __restrict__ ew,
                          float* deg, int* cnt, int E) {
    int e = blockIdx.x * blockDim.x + threadIdx.x;
    if (e < E) {
        int c = col[e];
        atomicAdd(&deg[c], ew[e]);
        atomicAdd(&cnt[c], 1);
    }
}

// single block: coalesced wave-scan of cnt -> rptr/cur (rsqrt moved to k_fill)
__global__ __launch_bounds__(1024) void k_scan(const int* __restrict__ cnt,
                                               int* __restrict__ rptr,
                                               int* __restrict__ cur, int n) {
    const int tid = threadIdx.x, lane = tid & 63, wv = tid >> 6;   // 16 waves
    const int chunk = (n + 15) >> 4;
    const int wbeg = wv * chunk;
    const int wend = min(wbeg + chunk, n);

    int tot = 0;
    for (int i = wbeg + lane; i < wend; i += 64) tot += cnt[i];
#pragma unroll
    for (int off = 32; off > 0; off >>= 1) tot += __shfl_xor(tot, off);
    __shared__ int woff[17];
    if (lane == 0) woff[wv] = tot;
    __syncthreads();
    if (tid == 0) {
        int r = 0;
        for (int w = 0; w < 16; ++w) { int t = woff[w]; woff[w] = r; r += t; }
        woff[16] = r;
    }
    __syncthreads();

    int run = woff[wv];
    for (int base = wbeg; base < wend; base += 64) {
        int i = base + lane;
        int v = (i < wend) ? cnt[i] : 0;
        int inc = v;
#pragma unroll
        for (int off = 1; off < 64; off <<= 1) {
            int u = __shfl_up(inc, off);
            if (lane >= off) inc += u;
        }
        if (i < wend) {
            int excl = run + inc - v;
            rptr[i] = excl;
            cur[i] = excl;
        }
        run += __shfl(inc, 63);
    }
    if (tid == 0) rptr[n] = woff[16];
}

// fused self-loop + edge fill; computes dinv from deg on the fly
__global__ void k_fill(const int* __restrict__ row, const int* __restrict__ col,
                       const float* __restrict__ ew, const float* __restrict__ deg,
                       int* cur, uint2* __restrict__ srcval, int N, int E) {
    int i = blockIdx.x * blockDim.x + threadIdx.x;
    if (i < N) {
        int slot = atomicAdd(&cur[i], 1);
        uint2 sv; sv.x = (unsigned)i; sv.y = __float_as_uint(1.0f / deg[i]);
        srcval[slot] = sv;
    } else if (i < N + E) {
        int e = i - N;
        int r = row[e], c = col[e];
        int slot = atomicAdd(&cur[c], 1);
        uint2 sv; sv.x = (unsigned)r;
        sv.y = __float_as_uint(rsqrtf(deg[r]) * ew[e] * rsqrtf(deg[c]));
        srcval[slot] = sv;
    }
}

// ---------------- bf16 GEMM: H[M][512] = A[M][512] @ W[512][512]^T ----------------
// BM=128, BN=256, BK=32, 512 threads (8 waves 2x4). Depth-2 pipeline:
// 3 LDS buffers, counted s_waitcnt vmcnt(N) (never drains the whole queue in
// steady state), ONE raw s_barrier per K-step.
//   iter t: vmcnt(3)  [own tile-t loads done; tile-t+1's 3 stay in flight]
//           s_barrier [=> ALL waves' tile-t loads landed; all prior ds_reads
//                       of buf[(t-1)%3] were consumed by MFMA before barrier]
//           STAGE(t+2) [writes buf[(t+2)%3] == buf[(t-1)%3] -- safe]
//           ds_read buf[t%3] -> 16 MFMA
__global__ __launch_bounds__(512) void k_gemm(
    const short* __restrict__ A,
    const short* __restrict__ W,
    short* __restrict__ H,
    int Mpad) {
    __shared__ short As[3][128 * 32];   // 24 KB
    __shared__ short Bs[3][256 * 32];   // 48 KB  (72 KB total -> 2 blocks/CU)
    const int tid = threadIdx.x;
    const int wave = tid >> 6, lane = tid & 63;
    const int wm = (wave >> 2) * 64, wn = (wave & 3) * 64;
    const int tm = blockIdx.x * 128, tn = blockIdx.y * 256;
    f32x4 acc[4][4] = {};
    const int fr = lane & 15, fc = lane >> 4;

    const int r0 = tid >> 2, cb0 = (tid & 3) * 8;   // 128 rows x 4 chunks of 8
    const short* Ab = A + (size_t)(tm + r0) * 512 + cb0;
    const short* Wb = W + (size_t)(tn + r0) * 512 + cb0;

#define STAGE(t)                                                            \
    {                                                                       \
        const int _k = (t) * 32, _b = (t) % 3;                              \
        gload_lds16(Ab + _k,                     &As[_b][tid * 8]);         \
        gload_lds16(Wb + _k,                     &Bs[_b][tid * 8]);         \
        gload_lds16(Wb + (size_t)128 * 512 + _k, &Bs[_b][(tid + 512) * 8]); \
    }

    STAGE(0);
    STAGE(1);
#pragma unroll
    for (int t = 0; t < 16; ++t) {
        if (t < 15) asm volatile("s_waitcnt vmcnt(3)" ::: "memory");
        else        asm volatile("s_waitcnt vmcnt(0)" ::: "memory");
        __builtin_amdgcn_s_barrier();
        asm volatile("" ::: "memory");
        if (t < 14) STAGE(t + 2);
        const int b = t % 3;
        bf16x8 af[4], bfr[4];
#pragma unroll
        for (int m = 0; m < 4; ++m)
            af[m] = *(const bf16x8*)&As[b][(wm + m * 16 + fr) * 32 + fc * 8];
#pragma unroll
        for (int n = 0; n < 4; ++n)
            bfr[n] = *(const bf16x8*)&Bs[b][(wn + n * 16 + fr) * 32 + fc * 8];
#pragma unroll
        for (int m = 0; m < 4; ++m) {
#pragma unroll
            for (int n = 0; n < 4; ++n)
                acc[m][n] = __builtin_amdgcn_mfma_f32_16x16x32_bf16(af[m], bfr[n], acc[m][n], 0, 0, 0);
        }
    }
#undef STAGE
    // C/D layout: col = lane&15, row = (lane>>4)*4 + j
    const int cbase = tn + wn + (lane & 15);
    const int rbase = tm + wm + fc * 4;
#pragma unroll
    for (int m = 0; m < 4; ++m) {
#pragma unroll
        for (int n = 0; n < 4; ++n) {
#pragma unroll
            for (int j = 0; j < 4; ++j) {
                int r = rbase + m * 16 + j;
                int c = cbase + n * 16;
                H[(size_t)r * 512 + c] = (short)f32_to_bf16_bits(acc[m][n][j]);
            }
        }
    }
}

// ---------------- fused aggregate + bias + LN + relu + residual ----------------
// ONE WAVE per target node. Lane owns 8 cols (uint4 gathers). Edge (src,val)
// loaded coalesced 64-at-a-time, broadcast via shfl. x2 unroll, dual acc banks.
__global__ __launch_bounds__(256) void k_agg_ln(
    const uint4* __restrict__ H4,       // h bf16 [Mpad][64] uint4
    const int* __restrict__ rptr,
    const uint2* __restrict__ srcval,
    const float4* __restrict__ bias,
    const float4* __restrict__ gamma,
    const float4* __restrict__ beta,
    uint4* __restrict__ xb,             // bf16 x: identity in, next-x out
    float4* __restrict__ out_f32,       // final f32 out (last layer)
    int N, int last) {
    const int wv = threadIdx.x >> 6, lane = threadIdx.x & 63;
    const int t = blockIdx.x * 4 + wv;
    if (t >= N) return;
    const int beg = rptr[t], end = rptr[t + 1];

    float a[8], b[8];
#pragma unroll
    for (int i = 0; i < 8; ++i) { a[i] = 0.f; b[i] = 0.f; }

    for (int base = beg; base < end; base += 64) {
        int m = end - base;
        if (m > 64) m = 64;
        int idx = base + lane;
        if (idx > end - 1) idx = end - 1;
        uint2 svl = srcval[idx];
        int e = 0;
        for (; e + 2 <= m; e += 2) {
            unsigned s0 = __shfl(svl.x, e);
            unsigned s1 = __shfl(svl.x, e + 1);
            float w0 = __uint_as_float(__shfl(svl.y, e));
            float w1 = __uint_as_float(__shfl(svl.y, e + 1));
            uint4 u0 = H4[(size_t)s0 * 64 + lane];
            uint4 u1 = H4[(size_t)s1 * 64 + lane];
            a[0] = fmaf(w0, bf16lo(u0.x), a[0]);
            a[1] = fmaf(w0, bf16hi(u0.x), a[1]);
            a[2] = fmaf(w0, bf16lo(u0.y), a[2]);
            a[3] = fmaf(w0, bf16hi(u0.y), a[3]);
            a[4] = fmaf(w0, bf16lo(u0.z), a[4]);
            a[5] = fmaf(w0, bf16hi(u0.z), a[5]);
            a[6] = fmaf(w0, bf16lo(u0.w), a[6]);
            a[7] = fmaf(w0, bf16hi(u0.w), a[7]);
            b[0] = fmaf(w1, bf16lo(u1.x), b[0]);
            b[1] = fmaf(w1, bf16hi(u1.x), b[1]);
            b[2] = fmaf(w1, bf16lo(u1.y), b[2]);
            b[3] = fmaf(w1, bf16hi(u1.y), b[3]);
            b[4] = fmaf(w1, bf16lo(u1.z), b[4]);
            b[5] = fmaf(w1, bf16hi(u1.z), b[5]);
            b[6] = fmaf(w1, bf16lo(u1.w), b[6]);
            b[7] = fmaf(w1, bf16hi(u1.w), b[7]);
        }
        if (e < m) {
            unsigned s0 = __shfl(svl.x, e);
            float w0 = __uint_as_float(__shfl(svl.y, e));
            uint4 u0 = H4[(size_t)s0 * 64 + lane];
            a[0] = fmaf(w0, bf16lo(u0.x), a[0]);
            a[1] = fmaf(w0, bf16hi(u0.x), a[1]);
            a[2] = fmaf(w0, bf16lo(u0.y), a[2]);
            a[3] = fmaf(w0, bf16hi(u0.y), a[3]);
            a[4] = fmaf(w0, bf16lo(u0.z), a[4]);
            a[5] = fmaf(w0, bf16hi(u0.z), a[5]);
            a[6] = fmaf(w0, bf16lo(u0.w), a[6]);
            a[7] = fmaf(w0, bf16hi(u0.w), a[7]);
        }
    }
#pragma unroll
    for (int i = 0; i < 8; ++i) a[i] += b[i];

    float4 bv0 = bias[lane * 2], bv1 = bias[lane * 2 + 1];
    a[0] += bv0.x; a[1] += bv0.y; a[2] += bv0.z; a[3] += bv0.w;
    a[4] += bv1.x; a[5] += bv1.y; a[6] += bv1.z; a[7] += bv1.w;

    float s1 = 0.f, s2 = 0.f;
#pragma unroll
    for (int i = 0; i < 8; ++i) { s1 += a[i]; s2 += a[i] * a[i]; }
#pragma unroll
    for (int off = 32; off > 0; off >>= 1) {
        s1 += __shfl_xor(s1, off);
        s2 += __shfl_xor(s2, off);
    }
    const float mean = s1 * (1.0f / 512.0f);
    const float var = s2 * (1.0f / 512.0f) - mean * mean;
    const float rstd = rsqrtf(var + LN_EPS);

    float4 gv0 = gamma[lane * 2], gv1 = gamma[lane * 2 + 1];
    float4 bt0 = beta[lane * 2], bt1 = beta[lane * 2 + 1];
    float o[8];
    o[0] = (a[0] - mean) * rstd * gv0.x + bt0.x;
    o[1] = (a[1] - mean) * rstd * gv0.y + bt0.y;
    o[2] = (a[2] - mean) * rstd * gv0.z + bt0.z;
    o[3] = (a[3] - mean) * rstd * gv0.w + bt0.w;
    o[4] = (a[4] - mean) * rstd * gv1.x + bt1.x;
    o[5] = (a[5] - mean) * rstd * gv1.y + bt1.y;
    o[6] = (a[6] - mean) * rstd * gv1.z + bt1.z;
    o[7] = (a[7] - mean) * rstd * gv1.w + bt1.w;
    if (!last) {
#pragma unroll
        for (int i = 0; i < 8; ++i) o[i] = fmaxf(o[i], 0.f);
    }
    uint4 idu = xb[(size_t)t * 64 + lane];
    o[0] += bf16lo(idu.x); o[1] += bf16hi(idu.x);
    o[2] += bf16lo(idu.y); o[3] += bf16hi(idu.y);
    o[4] += bf16lo(idu.z); o[5] += bf16hi(idu.z);
    o[6] += bf16lo(idu.w); o[7] += bf16hi(idu.w);

    if (last) {
        float4 f0, f1;
        f0.x = o[0]; f0.y = o[1]; f0.z = o[2]; f0.w = o[3];
        f1.x = o[4]; f1.y = o[5]; f1.z = o[6]; f1.w = o[7];
        out_f32[(size_t)t * 128 + lane * 2] = f0;
        out_f32[(size_t)t * 128 + lane * 2 + 1] = f1;
    } else {
        uint4 pk;
        pk.x = ((unsigned)f32_to_bf16_bits(o[1]) << 16) | f32_to_bf16_bits(o[0]);
        pk.y = ((unsigned)f32_to_bf16_bits(o[3]) << 16) | f32_to_bf16_bits(o[2]);
        pk.z = ((unsigned)f32_to_bf16_bits(o[5]) << 16) | f32_to_bf16_bits(o[4]);
        pk.w = ((unsigned)f32_to_bf16_bits(o[7]) << 16) | f32_to_bf16_bits(o[6]);
        xb[(size_t)t * 64 + lane] = pk;
    }
}

extern "C" void kernel_launch(void* const* d_in, const int* in_sizes, int n_in,
                              void* d_out, int out_size, void* d_ws, size_t ws_size,
                              hipStream_t stream) {
    const float* x0     = (const float*)d_in[0];
    const int*   ei     = (const int*)d_in[1];
    const float* ew     = (const float*)d_in[2];
    const float* Ws     = (const float*)d_in[3];
    const float* bs     = (const float*)d_in[4];
    const float* gammas = (const float*)d_in[5];
    const float* betas  = (const float*)d_in[6];

    const int N = in_sizes[0] / D;         // 50000
    const int E = in_sizes[1] / 2;         // 800000
    const int L = in_sizes[3] / (D * D);   // 3
    const int Mpad = (N + 127) & ~127;     // 50048

    char* p = (char*)d_ws;
    auto carve = [&](size_t bytes) {
        char* q = p;
        p += (bytes + 255) & ~(size_t)255;
        return (void*)q;
    };
    short* xb     = (short*)carve((size_t)Mpad * D * 2);   // x bf16 (padded)
    short* hb     = (short*)carve((size_t)Mpad * D * 2);   // h bf16 (padded)
    short* wb     = (short*)carve((size_t)L * D * D * 2);  // W bf16
    float* deg    = (float*)carve((size_t)N * 4);
    int*   cnt    = (int*)carve((size_t)N * 4);
    int*   rptr   = (int*)carve((size_t)(N + 1) * 4);
    int*   cur    = (int*)carve((size_t)N * 4);
    uint2* srcval = (uint2*)carve((size_t)(E + N) * 8);
    (void)ws_size; (void)n_in; (void)out_size;

    const int* rowI = ei;
    const int* colI = ei + E;

    // fused preprocessing: cast x0 (+pad), cast W, init deg/cnt
    {
        long nx4 = (long)Mpad * D / 4, nxin4 = (long)N * D / 4;
        long nw4 = (long)L * D * D / 4;
        long tot = nx4 + nw4 + N;
        k_prep<<<(int)((tot + 255) / 256), 256, 0, stream>>>(
            (const float4*)x0, (ushort4*)xb, (const float4*)Ws, (ushort4*)wb,
            deg, cnt, nx4, nxin4, nw4, N);
    }
    k_deg_cnt<<<(E + 255) / 256, 256, 0, stream>>>(colI, ew, deg, cnt, E);
    k_scan<<<1, 1024, 0, stream>>>(cnt, rptr, cur, N);
    k_fill<<<(N + E + 255) / 256, 256, 0, stream>>>(rowI, colI, ew, deg, cur, srcval, N, E);

    for (int l = 0; l < L; ++l) {
        dim3 g(Mpad / 128, D / 256);
        k_gemm<<<g, 512, 0, stream>>>(xb, wb + (size_t)l * D * D, hb, Mpad);
        int last = (l == L - 1);
        k_agg_ln<<<(N + 3) / 4, 256, 0, stream>>>(
            (const uint4*)hb, rptr, srcval,
            (const float4*)(bs + (size_t)l * D),
            (const float4*)(gammas + (size_t)l * D),
            (const float4*)(betas + (size_t)l * D),
            (uint4*)xb, (float4*)d_out, N, last);
    }
}

// Round 11
// 654.831 us; speedup vs baseline: 1.3642x; 1.0464x over previous
//
#include <hip/hip_runtime.h>
#include <hip/hip_bf16.h>
#include <stdint.h>

#define D 512
#define LN_EPS 1e-5f
#define TWO32 4294967296.0

typedef __attribute__((ext_vector_type(8))) short bf16x8;
typedef __attribute__((ext_vector_type(4))) float f32x4;

__device__ __forceinline__ unsigned short f32_to_bf16_bits(float x) {
    unsigned int u = __float_as_uint(x);
    u += 0x7fffu + ((u >> 16) & 1u);   // round-to-nearest-even
    return (unsigned short)(u >> 16);
}
__device__ __forceinline__ float bf16lo(unsigned int u) { return __uint_as_float(u << 16); }
__device__ __forceinline__ float bf16hi(unsigned int u) { return __uint_as_float(u & 0xffff0000u); }

// unpack from packed double (cnt*2^32 + deg): both exact (pow2 scale / exact sub)
__device__ __forceinline__ float unpack_deg(double d) {
    int c = (int)(d * (1.0 / TWO32));
    return (float)(d - TWO32 * (double)c);
}
__device__ __forceinline__ int unpack_cnt(double d) {
    return (int)(d * (1.0 / TWO32));
}

typedef const __attribute__((address_space(1))) unsigned int GU;
typedef __attribute__((address_space(3))) unsigned int LU;
__device__ __forceinline__ void gload_lds16(const void* g, void* l) {
    __builtin_amdgcn_global_load_lds((GU*)g, (LU*)l, 16, 0, 0);
}

// ---------------- fused preprocessing: cast x0, cast W, init packed deg/cnt ----------------
__global__ void k_prep(const float4* __restrict__ x0, ushort4* __restrict__ xb4,
                       const float4* __restrict__ Ws4, ushort4* __restrict__ wb4,
                       double* __restrict__ dp,
                       long nx4, long nxin4, long nw4, int N) {
    long id = (long)blockIdx.x * blockDim.x + threadIdx.x;
    if (id < nx4) {
        float4 v;
        if (id < nxin4) v = x0[id];
        else { v.x = 0.f; v.y = 0.f; v.z = 0.f; v.w = 0.f; }
        ushort4 o;
        o.x = f32_to_bf16_bits(v.x);
        o.y = f32_to_bf16_bits(v.y);
        o.z = f32_to_bf16_bits(v.z);
        o.w = f32_to_bf16_bits(v.w);
        xb4[id] = o;
    } else if (id < nx4 + nw4) {
        long i = id - nx4;
        float4 v = Ws4[i];
        ushort4 o;
        o.x = f32_to_bf16_bits(v.x);
        o.y = f32_to_bf16_bits(v.y);
        o.z = f32_to_bf16_bits(v.z);
        o.w = f32_to_bf16_bits(v.w);
        wb4[i] = o;
    } else {
        long i = id - nx4 - nw4;
        if (i < N) dp[i] = TWO32 + 1.0;   // self-loop: cnt 1, weight 1
    }
}

// one packed double atomic per edge: cnt += 1 (upper), deg += ew (lower)
__global__ void k_deg_cnt(const int* __restrict__ col, const float* __restrict__ ew,
                          double* dp, int E) {
    int e = blockIdx.x * blockDim.x + threadIdx.x;
    if (e < E) atomicAdd(&dp[col[e]], TWO32 + (double)ew[e]);
}

// single block: coalesced wave-scan of cnt (unpacked from dp) -> rptr/cur
__global__ __launch_bounds__(1024) void k_scan(const double* __restrict__ dp,
                                               int* __restrict__ rptr,
                                               int* __restrict__ cur, int n) {
    const int tid = threadIdx.x, lane = tid & 63, wv = tid >> 6;   // 16 waves
    const int chunk = (n + 15) >> 4;
    const int wbeg = wv * chunk;
    const int wend = min(wbeg + chunk, n);

    int tot = 0;
    for (int i = wbeg + lane; i < wend; i += 64) tot += unpack_cnt(dp[i]);
#pragma unroll
    for (int off = 32; off > 0; off >>= 1) tot += __shfl_xor(tot, off);
    __shared__ int woff[17];
    if (lane == 0) woff[wv] = tot;
    __syncthreads();
    if (tid == 0) {
        int r = 0;
        for (int w = 0; w < 16; ++w) { int t = woff[w]; woff[w] = r; r += t; }
        woff[16] = r;
    }
    __syncthreads();

    int run = woff[wv];
    for (int base = wbeg; base < wend; base += 64) {
        int i = base + lane;
        int v = (i < wend) ? unpack_cnt(dp[i]) : 0;
        int inc = v;
#pragma unroll
        for (int off = 1; off < 64; off <<= 1) {
            int u = __shfl_up(inc, off);
            if (lane >= off) inc += u;
        }
        if (i < wend) {
            int excl = run + inc - v;
            rptr[i] = excl;
            cur[i] = excl;
        }
        run += __shfl(inc, 63);
    }
    if (tid == 0) rptr[n] = woff[16];
}

// fused self-loop + edge fill; dinv from packed deg on the fly
__global__ void k_fill(const int* __restrict__ row, const int* __restrict__ col,
                       const float* __restrict__ ew, const double* __restrict__ dp,
                       int* cur, uint2* __restrict__ srcval, int N, int E) {
    int i = blockIdx.x * blockDim.x + threadIdx.x;
    if (i < N) {
        int slot = atomicAdd(&cur[i], 1);
        uint2 sv; sv.x = (unsigned)i;
        sv.y = __float_as_uint(1.0f / unpack_deg(dp[i]));
        srcval[slot] = sv;
    } else if (i < N + E) {
        int e = i - N;
        int r = row[e], c = col[e];
        int slot = atomicAdd(&cur[c], 1);
        uint2 sv; sv.x = (unsigned)r;
        sv.y = __float_as_uint(rsqrtf(unpack_deg(dp[r])) * ew[e] * rsqrtf(unpack_deg(dp[c])));
        srcval[slot] = sv;
    }
}

// ---------------- bf16 GEMM: H[M][512] = A[M][512] @ W[512][512]^T ----------------
// BM=128, BN=256, BK=32, 512 threads (8 waves 2x4). Depth-2 pipeline:
// 3 LDS buffers, counted vmcnt, ONE raw s_barrier per K-step (r9-verified).
// Epilogue: wave-local LDS repack -> coalesced bf16x8 stores.
// ROW STRIDE 72 shorts (144B, multiple of 16B): r10's stride 68 (136B) made
// odd rows 8-mod-16 aligned -> misaligned ds_read_b128 -> garbage (absmax 1.05).
__global__ __launch_bounds__(512) void k_gemm(
    const short* __restrict__ A,
    const short* __restrict__ W,
    short* __restrict__ H,
    int Mpad) {
    __shared__ short smem[3 * 128 * 32 + 3 * 256 * 32];   // 72 KB (= 8 waves x 64 x 72 exactly)
    short (*As)[128 * 32] = (short(*)[128 * 32])smem;
    short (*Bs)[256 * 32] = (short(*)[256 * 32])(smem + 3 * 128 * 32);
    const int tid = threadIdx.x;
    const int wave = tid >> 6, lane = tid & 63;
    const int wm = (wave >> 2) * 64, wn = (wave & 3) * 64;
    const int tm = blockIdx.x * 128, tn = blockIdx.y * 256;
    f32x4 acc[4][4] = {};
    const int fr = lane & 15, fc = lane >> 4;

    const int r0 = tid >> 2, cb0 = (tid & 3) * 8;   // 128 rows x 4 chunks of 8
    const short* Ab = A + (size_t)(tm + r0) * 512 + cb0;
    const short* Wb = W + (size_t)(tn + r0) * 512 + cb0;

#define STAGE(t)                                                            \
    {                                                                       \
        const int _k = (t) * 32, _b = (t) % 3;                              \
        gload_lds16(Ab + _k,                     &As[_b][tid * 8]);         \
        gload_lds16(Wb + _k,                     &Bs[_b][tid * 8]);         \
        gload_lds16(Wb + (size_t)128 * 512 + _k, &Bs[_b][(tid + 512) * 8]); \
    }

    STAGE(0);
    STAGE(1);
#pragma unroll
    for (int t = 0; t < 16; ++t) {
        if (t < 15) asm volatile("s_waitcnt vmcnt(3)" ::: "memory");
        else        asm volatile("s_waitcnt vmcnt(0)" ::: "memory");
        __builtin_amdgcn_s_barrier();
        asm volatile("" ::: "memory");
        if (t < 14) STAGE(t + 2);
        const int b = t % 3;
        bf16x8 af[4], bfr[4];
#pragma unroll
        for (int m = 0; m < 4; ++m)
            af[m] = *(const bf16x8*)&As[b][(wm + m * 16 + fr) * 32 + fc * 8];
#pragma unroll
        for (int n = 0; n < 4; ++n)
            bfr[n] = *(const bf16x8*)&Bs[b][(wn + n * 16 + fr) * 32 + fc * 8];
#pragma unroll
        for (int m = 0; m < 4; ++m) {
#pragma unroll
            for (int n = 0; n < 4; ++n)
                acc[m][n] = __builtin_amdgcn_mfma_f32_16x16x32_bf16(af[m], bfr[n], acc[m][n], 0, 0, 0);
        }
    }
#undef STAGE

    // all waves done reading staging LDS before we overwrite it
    __syncthreads();

    // wave-local repack: rows 0..63 = m*16+fc*4+j, cols 0..63 = n*16+fr.
    // stride 72 shorts = 144B (16B-aligned rows; read-phase banks: 8-phase optimal)
    short* wlds = smem + wave * (64 * 72);
#pragma unroll
    for (int m = 0; m < 4; ++m) {
#pragma unroll
        for (int n = 0; n < 4; ++n) {
#pragma unroll
            for (int j = 0; j < 4; ++j)
                wlds[(m * 16 + fc * 4 + j) * 72 + n * 16 + fr] =
                    (short)f32_to_bf16_bits(acc[m][n][j]);
        }
    }
    asm volatile("s_waitcnt lgkmcnt(0)" ::: "memory");   // cross-lane ds_write -> ds_read
    __builtin_amdgcn_sched_barrier(0);

    const int ch = lane & 7, rg = lane >> 3;
#pragma unroll
    for (int i = 0; i < 8; ++i) {
        const int rrow = i * 8 + rg;
        bf16x8 v = *(const bf16x8*)&wlds[rrow * 72 + ch * 8];
        *(bf16x8*)&H[(size_t)(tm + wm + rrow) * 512 + tn + wn + ch * 8] = v;
    }
}

// ---------------- fused aggregate + bias + LN + relu + residual ----------------
// ONE WAVE per target node. Lane owns 8 cols (uint4 gathers). Edge (src,val)
// loaded coalesced 64-at-a-time, broadcast via shfl. x2 unroll, dual acc banks.
__global__ __launch_bounds__(256) void k_agg_ln(
    const uint4* __restrict__ H4,       // h bf16 [Mpad][64] uint4
    const int* __restrict__ rptr,
    const uint2* __restrict__ srcval,
    const float4* __restrict__ bias,
    const float4* __restrict__ gamma,
    const float4* __restrict__ beta,
    uint4* __restrict__ xb,             // bf16 x: identity in, next-x out
    float4* __restrict__ out_f32,       // final f32 out (last layer)
    int N, int last) {
    const int wv = threadIdx.x >> 6, lane = threadIdx.x & 63;
    const int t = blockIdx.x * 4 + wv;
    if (t >= N) return;
    const int beg = rptr[t], end = rptr[t + 1];

    float a[8], b[8];
#pragma unroll
    for (int i = 0; i < 8; ++i) { a[i] = 0.f; b[i] = 0.f; }

    for (int base = beg; base < end; base += 64) {
        int m = end - base;
        if (m > 64) m = 64;
        int idx = base + lane;
        if (idx > end - 1) idx = end - 1;
        uint2 svl = srcval[idx];
        int e = 0;
        for (; e + 2 <= m; e += 2) {
            unsigned s0 = __shfl(svl.x, e);
            unsigned s1 = __shfl(svl.x, e + 1);
            float w0 = __uint_as_float(__shfl(svl.y, e));
            float w1 = __uint_as_float(__shfl(svl.y, e + 1));
            uint4 u0 = H4[(size_t)s0 * 64 + lane];
            uint4 u1 = H4[(size_t)s1 * 64 + lane];
            a[0] = fmaf(w0, bf16lo(u0.x), a[0]);
            a[1] = fmaf(w0, bf16hi(u0.x), a[1]);
            a[2] = fmaf(w0, bf16lo(u0.y), a[2]);
            a[3] = fmaf(w0, bf16hi(u0.y), a[3]);
            a[4] = fmaf(w0, bf16lo(u0.z), a[4]);
            a[5] = fmaf(w0, bf16hi(u0.z), a[5]);
            a[6] = fmaf(w0, bf16lo(u0.w), a[6]);
            a[7] = fmaf(w0, bf16hi(u0.w), a[7]);
            b[0] = fmaf(w1, bf16lo(u1.x), b[0]);
            b[1] = fmaf(w1, bf16hi(u1.x), b[1]);
            b[2] = fmaf(w1, bf16lo(u1.y), b[2]);
            b[3] = fmaf(w1, bf16hi(u1.y), b[3]);
            b[4] = fmaf(w1, bf16lo(u1.z), b[4]);
            b[5] = fmaf(w1, bf16hi(u1.z), b[5]);
            b[6] = fmaf(w1, bf16lo(u1.w), b[6]);
            b[7] = fmaf(w1, bf16hi(u1.w), b[7]);
        }
        if (e < m) {
            unsigned s0 = __shfl(svl.x, e);
            float w0 = __uint_as_float(__shfl(svl.y, e));
            uint4 u0 = H4[(size_t)s0 * 64 + lane];
            a[0] = fmaf(w0, bf16lo(u0.x), a[0]);
            a[1] = fmaf(w0, bf16hi(u0.x), a[1]);
            a[2] = fmaf(w0, bf16lo(u0.y), a[2]);
            a[3] = fmaf(w0, bf16hi(u0.y), a[3]);
            a[4] = fmaf(w0, bf16lo(u0.z), a[4]);
            a[5] = fmaf(w0, bf16hi(u0.z), a[5]);
            a[6] = fmaf(w0, bf16lo(u0.w), a[6]);
            a[7] = fmaf(w0, bf16hi(u0.w), a[7]);
        }
    }
#pragma unroll
    for (int i = 0; i < 8; ++i) a[i] += b[i];

    float4 bv0 = bias[lane * 2], bv1 = bias[lane * 2 + 1];
    a[0] += bv0.x; a[1] += bv0.y; a[2] += bv0.z; a[3] += bv0.w;
    a[4] += bv1.x; a[5] += bv1.y; a[6] += bv1.z; a[7] += bv1.w;

    float s1 = 0.f, s2 = 0.f;
#pragma unroll
    for (int i = 0; i < 8; ++i) { s1 += a[i]; s2 += a[i] * a[i]; }
#pragma unroll
    for (int off = 32; off > 0; off >>= 1) {
        s1 += __shfl_xor(s1, off);
        s2 += __shfl_xor(s2, off);
    }
    const float mean = s1 * (1.0f / 512.0f);
    const float var = s2 * (1.0f / 512.0f) - mean * mean;
    const float rstd = rsqrtf(var + LN_EPS);

    float4 gv0 = gamma[lane * 2], gv1 = gamma[lane * 2 + 1];
    float4 bt0 = beta[lane * 2], bt1 = beta[lane * 2 + 1];
    float o[8];
    o[0] = (a[0] - mean) * rstd * gv0.x + bt0.x;
    o[1] = (a[1] - mean) * rstd * gv0.y + bt0.y;
    o[2] = (a[2] - mean) * rstd * gv0.z + bt0.z;
    o[3] = (a[3] - mean) * rstd * gv0.w + bt0.w;
    o[4] = (a[4] - mean) * rstd * gv1.x + bt1.x;
    o[5] = (a[5] - mean) * rstd * gv1.y + bt1.y;
    o[6] = (a[6] - mean) * rstd * gv1.z + bt1.z;
    o[7] = (a[7] - mean) * rstd * gv1.w + bt1.w;
    if (!last) {
#pragma unroll
        for (int i = 0; i < 8; ++i) o[i] = fmaxf(o[i], 0.f);
    }
    uint4 idu = xb[(size_t)t * 64 + lane];
    o[0] += bf16lo(idu.x); o[1] += bf16hi(idu.x);
    o[2] += bf16lo(idu.y); o[3] += bf16hi(idu.y);
    o[4] += bf16lo(idu.z); o[5] += bf16hi(idu.z);
    o[6] += bf16lo(idu.w); o[7] += bf16hi(idu.w);

    if (last) {
        float4 f0, f1;
        f0.x = o[0]; f0.y = o[1]; f0.z = o[2]; f0.w = o[3];
        f1.x = o[4]; f1.y = o[5]; f1.z = o[6]; f1.w = o[7];
        out_f32[(size_t)t * 128 + lane * 2] = f0;
        out_f32[(size_t)t * 128 + lane * 2 + 1] = f1;
    } else {
        uint4 pk;
        pk.x = ((unsigned)f32_to_bf16_bits(o[1]) << 16) | f32_to_bf16_bits(o[0]);
        pk.y = ((unsigned)f32_to_bf16_bits(o[3]) << 16) | f32_to_bf16_bits(o[2]);
        pk.z = ((unsigned)f32_to_bf16_bits(o[5]) << 16) | f32_to_bf16_bits(o[4]);
        pk.w = ((unsigned)f32_to_bf16_bits(o[7]) << 16) | f32_to_bf16_bits(o[6]);
        xb[(size_t)t * 64 + lane] = pk;
    }
}

extern "C" void kernel_launch(void* const* d_in, const int* in_sizes, int n_in,
                              void* d_out, int out_size, void* d_ws, size_t ws_size,
                              hipStream_t stream) {
    const float* x0     = (const float*)d_in[0];
    const int*   ei     = (const int*)d_in[1];
    const float* ew     = (const float*)d_in[2];
    const float* Ws     = (const float*)d_in[3];
    const float* bs     = (const float*)d_in[4];
    const float* gammas = (const float*)d_in[5];
    const float* betas  = (const float*)d_in[6];

    const int N = in_sizes[0] / D;         // 50000
    const int E = in_sizes[1] / 2;         // 800000
    const int L = in_sizes[3] / (D * D);   // 3
    const int Mpad = (N + 127) & ~127;     // 50048

    char* p = (char*)d_ws;
    auto carve = [&](size_t bytes) {
        char* q = p;
        p += (bytes + 255) & ~(size_t)255;
        return (void*)q;
    };
    short*  xb     = (short*)carve((size_t)Mpad * D * 2);   // x bf16 (padded)
    short*  hb     = (short*)carve((size_t)Mpad * D * 2);   // h bf16 (padded)
    short*  wb     = (short*)carve((size_t)L * D * D * 2);  // W bf16
    double* dp     = (double*)carve((size_t)N * 8);         // packed cnt*2^32 + deg
    int*    rptr   = (int*)carve((size_t)(N + 1) * 4);
    int*    cur    = (int*)carve((size_t)N * 4);
    uint2*  srcval = (uint2*)carve((size_t)(E + N) * 8);
    (void)ws_size; (void)n_in; (void)out_size;

    const int* rowI = ei;
    const int* colI = ei + E;

    // fused preprocessing: cast x0 (+pad), cast W, init packed deg/cnt
    {
        long nx4 = (long)Mpad * D / 4, nxin4 = (long)N * D / 4;
        long nw4 = (long)L * D * D / 4;
        long tot = nx4 + nw4 + N;
        k_prep<<<(int)((tot + 255) / 256), 256, 0, stream>>>(
            (const float4*)x0, (ushort4*)xb, (const float4*)Ws, (ushort4*)wb,
            dp, nx4, nxin4, nw4, N);
    }
    k_deg_cnt<<<(E + 255) / 256, 256, 0, stream>>>(colI, ew, dp, E);
    k_scan<<<1, 1024, 0, stream>>>(dp, rptr, cur, N);
    k_fill<<<(N + E + 255) / 256, 256, 0, stream>>>(rowI, colI, ew, dp, cur, srcval, N, E);

    for (int l = 0; l < L; ++l) {
        dim3 g(Mpad / 128, D / 256);
        k_gemm<<<g, 512, 0, stream>>>(xb, wb + (size_t)l * D * D, hb, Mpad);
        int last = (l == L - 1);
        k_agg_ln<<<(N + 3) / 4, 256, 0, stream>>>(
            (const uint4*)hb, rptr, srcval,
            (const float4*)(bs + (size_t)l * D),
            (const float4*)(gammas + (size_t)l * D),
            (const float4*)(betas + (size_t)l * D),
            (uint4*)xb, (float4*)d_out, N, last);
    }
}